// Round 10
// baseline (602.651 us; speedup 1.0000x reference)
//
#include <hip/hip_runtime.h>
#include <hip/hip_bf16.h>

#define N_NODES 100000
#define N_EDGES 3200000
#define N_GRAPHS 512
#define NBUK 782               // dst buckets of 128 nodes: (100000+127)/128
#define CAP 4608               // slot capacity per bucket (mean 4092, sigma~64)
#define FILL_CHUNK 16384
#define FILL_BLOCKS ((N_EDGES + FILL_CHUNK - 1) / FILL_CHUNK)   // 196

__device__ __forceinline__ float blo(unsigned v) { return __uint_as_float(v << 16); }
__device__ __forceinline__ float bhi(unsigned v) { return __uint_as_float(v & 0xffff0000u); }

// ---------- pass 1: bin edges into fixed bucket slots (bucket = dst>>7) ----------
__global__ __launch_bounds__(1024) void k_binfill(const int* __restrict__ ei,
                                                  int* __restrict__ gcnt,
                                                  unsigned* __restrict__ packed) {
    __shared__ int h[NBUK];
    __shared__ int base[NBUK];
    int t = threadIdx.x;
    for (int i = t; i < NBUK; i += 1024) h[i] = 0;
    __syncthreads();
    int s0 = blockIdx.x * FILL_CHUNK;
    int ng = min(FILL_CHUNK, N_EDGES - s0) >> 2;   // 4-entry groups
    const int4* src4 = (const int4*)(ei + s0);
    const int4* dst4 = (const int4*)(ei + N_EDGES + s0);
    int4 sv[4], dv[4];
    int  rk[4][4];
#pragma unroll
    for (int g = 0; g < 4; g++) {
        int gi = t + g * 1024;
        if (gi < ng) {
            sv[g] = src4[gi];
            dv[g] = dst4[gi];
            rk[g][0] = atomicAdd(&h[dv[g].x >> 7], 1);
            rk[g][1] = atomicAdd(&h[dv[g].y >> 7], 1);
            rk[g][2] = atomicAdd(&h[dv[g].z >> 7], 1);
            rk[g][3] = atomicAdd(&h[dv[g].w >> 7], 1);
        }
    }
    __syncthreads();
    for (int i = t; i < NBUK; i += 1024) {
        int c = h[i];
        base[i] = c ? atomicAdd(&gcnt[i], c) : 0;
    }
    __syncthreads();
#pragma unroll
    for (int g = 0; g < 4; g++) {
        int gi = t + g * 1024;
        if (gi < ng) {
            int s[4] = {sv[g].x, sv[g].y, sv[g].z, sv[g].w};
            int d[4] = {dv[g].x, dv[g].y, dv[g].z, dv[g].w};
#pragma unroll
            for (int k = 0; k < 4; k++) {
                int bk = d[k] >> 7;
                int pos = bk * CAP + base[bk] + rk[g][k];
                packed[pos] = (unsigned)s[k] | (((unsigned)d[k] & 127u) << 17);
            }
        }
    }
}

// ---------- pass 2: per-bucket deg/scan -> rp/rpe/dinv/cnt + slotted CSR ----------
__global__ __launch_bounds__(512) void k_csr(const unsigned* __restrict__ packed,
                                             const int* __restrict__ gcnt,
                                             const int* __restrict__ batch,
                                             int* __restrict__ rp, int* __restrict__ rpe,
                                             float* __restrict__ dinv,
                                             int* __restrict__ csr, int* __restrict__ cnt) {
    __shared__ int deg[128];
    __shared__ int sd[128];
    __shared__ int nb0[128];
    int t = threadIdx.x;
    int b = blockIdx.x;
    if (t < 128) deg[t] = 0;
    __syncthreads();
    int n = gcnt[b];
    const unsigned* pb = packed + (size_t)b * CAP;
    unsigned pv[3][4];
    int rk[3][4];
#pragma unroll
    for (int g = 0; g < 3; g++) {
        int i0 = 4 * (t + g * 512);
        if (i0 < n) {
            uint4 p = *(const uint4*)(pb + i0);
            pv[g][0] = p.x; pv[g][1] = p.y; pv[g][2] = p.z; pv[g][3] = p.w;
#pragma unroll
            for (int k = 0; k < 4; k++)
                if (i0 + k < n) rk[g][k] = atomicAdd(&deg[pv[g][k] >> 17], 1);
        }
    }
    __syncthreads();
    int d = (t < 128) ? deg[t] : 0;
    if (t < 128) sd[t] = d;
    __syncthreads();
    for (int off = 1; off < 128; off <<= 1) {
        int x = (t >= off && t < 128) ? sd[t - off] : 0;
        __syncthreads();
        if (t < 128) sd[t] += x;
        __syncthreads();
    }
    if (t < 128) {
        int pos0 = b * CAP + sd[t] - d;
        nb0[t] = pos0;
        int node = b * 128 + t;
        if (node < N_NODES) {
            rp[node] = pos0;
            rpe[node] = pos0 + d;
            dinv[node] = rsqrtf((float)d + 1.0f);
            atomicAdd(&cnt[batch[node]], 1);
        }
    }
    __syncthreads();
#pragma unroll
    for (int g = 0; g < 3; g++) {
        int i0 = 4 * (t + g * 512);
        if (i0 < n) {
#pragma unroll
            for (int k = 0; k < 4; k++) {
                if (i0 + k < n) {
                    unsigned p = pv[g][k];
                    csr[nb0[p >> 17] + rk[g][k]] = (int)(p & 0x1FFFFu);
                }
            }
        }
    }
}

// ---------- H1s = bf16( (x @ W1) * dinv[row] ) ----------
__global__ void k_gemm1(const float* __restrict__ x, const float* __restrict__ W1,
                        const float* __restrict__ dinv, __hip_bfloat16* __restrict__ H1s) {
    __shared__ float Ws[128 * 32];
    __shared__ float xs[32 * 128];
    int t = threadIdx.x;
    const float4* W4 = (const float4*)W1;
    float4* Ws4 = (float4*)Ws;
#pragma unroll
    for (int i = 0; i < 4; i++) Ws4[t + 256 * i] = W4[t + 256 * i];
    int row0 = blockIdx.x * 32;
    const float4* x4 = (const float4*)(x + (size_t)row0 * 128);
    float4* xs4 = (float4*)xs;
#pragma unroll
    for (int i = 0; i < 4; i++) xs4[t + 256 * i] = x4[t + 256 * i];
    __syncthreads();
    int col = t & 31;
    int rb = (t >> 5) * 4;
    float a0 = 0.f, a1 = 0.f, a2 = 0.f, a3 = 0.f;
#pragma unroll 8
    for (int k = 0; k < 128; k++) {
        float w = Ws[k * 32 + col];
        a0 += xs[(rb + 0) * 128 + k] * w;
        a1 += xs[(rb + 1) * 128 + k] * w;
        a2 += xs[(rb + 2) * 128 + k] * w;
        a3 += xs[(rb + 3) * 128 + k] * w;
    }
    int r = row0 + rb;
    __hip_bfloat16* o = H1s + (size_t)r * 32 + col;
    o[0]  = __float2bfloat16(a0 * dinv[r + 0]);
    o[32] = __float2bfloat16(a1 * dinv[r + 1]);
    o[64] = __float2bfloat16(a2 * dinv[r + 2]);
    o[96] = __float2bfloat16(a3 * dinv[r + 3]);
}

// ---------- layer-1 gather (uint4 rows) FUSED with layer-2 transform ----------
// lane = (q = lane>>2 edge slot 0..15, r = lane&3 16B chunk). One wave-instr
// fetches 16 full rows, 4 contiguous lanes per 64B line.
__global__ void k_gather1(const __hip_bfloat16* __restrict__ Hs, const float* __restrict__ dinv,
                          const int* __restrict__ rp, const int* __restrict__ rpe,
                          const int* __restrict__ csr,
                          const float* __restrict__ b1, const float* __restrict__ W2,
                          __hip_bfloat16* __restrict__ H2s) {
    int wid = (blockIdx.x * 256 + threadIdx.x) >> 6;
    if (wid >= N_NODES) return;
    const uint4* H16 = (const uint4*)Hs;   // row = 4 uint4
    int lane = threadIdx.x & 63;
    int r = lane & 3;
    int q = lane >> 2;
    int f = lane & 31;
    int half = lane >> 5;
    float w2r[16];
#pragma unroll
    for (int j = 0; j < 16; j++) w2r[j] = W2[(half * 16 + j) * 32 + f];
    int beg = rp[wid], end = rpe[wid];
    float a[8] = {0.f, 0.f, 0.f, 0.f, 0.f, 0.f, 0.f, 0.f};
    int e = beg + q;
    for (; e + 16 < end; e += 32) {
        int s0 = csr[e];
        int s1 = csr[e + 16];
        uint4 v0 = H16[(size_t)s0 * 4 + r];
        uint4 v1 = H16[(size_t)s1 * 4 + r];
        a[0] += blo(v0.x) + blo(v1.x); a[1] += bhi(v0.x) + bhi(v1.x);
        a[2] += blo(v0.y) + blo(v1.y); a[3] += bhi(v0.y) + bhi(v1.y);
        a[4] += blo(v0.z) + blo(v1.z); a[5] += bhi(v0.z) + bhi(v1.z);
        a[6] += blo(v0.w) + blo(v1.w); a[7] += bhi(v0.w) + bhi(v1.w);
    }
    for (; e < end; e += 16) {
        int s = csr[e];
        uint4 v = H16[(size_t)s * 4 + r];
        a[0] += blo(v.x); a[1] += bhi(v.x);
        a[2] += blo(v.y); a[3] += bhi(v.y);
        a[4] += blo(v.z); a[5] += bhi(v.z);
        a[6] += blo(v.w); a[7] += bhi(v.w);
    }
#pragma unroll
    for (int m = 4; m <= 32; m <<= 1) {
#pragma unroll
        for (int j = 0; j < 8; j++) a[j] += __shfl_xor(a[j], m);
    }
    // all lanes now hold the chunk-r sums; apply self-loop + bias + relu
    float di = dinv[wid];
    uint4 hw = H16[(size_t)wid * 4 + r];
    float hb[8] = {blo(hw.x), bhi(hw.x), blo(hw.y), bhi(hw.y),
                   blo(hw.z), bhi(hw.z), blo(hw.w), bhi(hw.w)};
    float4 bb0 = *(const float4*)(b1 + r * 8);
    float4 bb1 = *(const float4*)(b1 + r * 8 + 4);
    float bbv[8] = {bb0.x, bb0.y, bb0.z, bb0.w, bb1.x, bb1.y, bb1.z, bb1.w};
    float va[8];
#pragma unroll
    for (int j = 0; j < 8; j++)
        va[j] = fmaxf((a[j] + hb[j]) * di + bbv[j], 0.f);
    // h2[f] = sum_k relu_h1[k] * W2[k][f]; this lane covers k in [half*16, half*16+16)
    // relu_h1[k] lives in lane (k>>3) (q=0, r=k>>3), element k&7.
    float acc = 0.f;
#pragma unroll
    for (int j = 0; j < 16; j++)
        acc += __shfl(va[j & 7], (half << 1) + (j >> 3)) * w2r[j];
    acc += __shfl_xor(acc, 32);            // combine k-halves
    if (half == 0)
        H2s[(size_t)wid * 32 + f] = __float2bfloat16(acc * di);
}

// ---------- layer-2 aggregation (uint4 rows) fused with mean-pool numerator ----------
__global__ void k_gather2(const __hip_bfloat16* __restrict__ Hs, const float* __restrict__ dinv,
                          const int* __restrict__ rp, const int* __restrict__ rpe,
                          const int* __restrict__ csr,
                          const float* __restrict__ bias, const int* __restrict__ batch,
                          float* __restrict__ pool) {
    int wid = (blockIdx.x * 256 + threadIdx.x) >> 6;
    if (wid >= N_NODES) return;
    const uint4* H16 = (const uint4*)Hs;
    int lane = threadIdx.x & 63;
    int r = lane & 3;
    int q = lane >> 2;
    int beg = rp[wid], end = rpe[wid];
    float a[8] = {0.f, 0.f, 0.f, 0.f, 0.f, 0.f, 0.f, 0.f};
    int e = beg + q;
    for (; e + 16 < end; e += 32) {
        int s0 = csr[e];
        int s1 = csr[e + 16];
        uint4 v0 = H16[(size_t)s0 * 4 + r];
        uint4 v1 = H16[(size_t)s1 * 4 + r];
        a[0] += blo(v0.x) + blo(v1.x); a[1] += bhi(v0.x) + bhi(v1.x);
        a[2] += blo(v0.y) + blo(v1.y); a[3] += bhi(v0.y) + bhi(v1.y);
        a[4] += blo(v0.z) + blo(v1.z); a[5] += bhi(v0.z) + bhi(v1.z);
        a[6] += blo(v0.w) + blo(v1.w); a[7] += bhi(v0.w) + bhi(v1.w);
    }
    for (; e < end; e += 16) {
        int s = csr[e];
        uint4 v = H16[(size_t)s * 4 + r];
        a[0] += blo(v.x); a[1] += bhi(v.x);
        a[2] += blo(v.y); a[3] += bhi(v.y);
        a[4] += blo(v.z); a[5] += bhi(v.z);
        a[6] += blo(v.w); a[7] += bhi(v.w);
    }
#pragma unroll
    for (int m = 4; m <= 32; m <<= 1) {
#pragma unroll
        for (int j = 0; j < 8; j++) a[j] += __shfl_xor(a[j], m);
    }
    if (q == 0) {   // lanes 0..3, r = lane
        float di = dinv[wid];
        uint4 hw = H16[(size_t)wid * 4 + r];
        float hb[8] = {blo(hw.x), bhi(hw.x), blo(hw.y), bhi(hw.y),
                       blo(hw.z), bhi(hw.z), blo(hw.w), bhi(hw.w)};
        float4 bb0 = *(const float4*)(bias + r * 8);
        float4 bb1 = *(const float4*)(bias + r * 8 + 4);
        float bbv[8] = {bb0.x, bb0.y, bb0.z, bb0.w, bb1.x, bb1.y, bb1.z, bb1.w};
        int g = batch[wid];
#pragma unroll
        for (int j = 0; j < 8; j++) {
            float v = fmaxf((a[j] + hb[j]) * di + bbv[j], 0.f);
            atomicAdd(&pool[(size_t)g * 32 + r * 8 + j], v);
        }
    }
}

// ---------- head ----------
__global__ void k_final(const float* __restrict__ pool, const int* __restrict__ cnt,
                        const float* __restrict__ Wl, const float* __restrict__ bl,
                        float* __restrict__ out) {
    int g = blockIdx.x * 256 + threadIdx.x;
    if (g >= N_GRAPHS) return;
    float inv = 1.0f / fmaxf((float)cnt[g], 1.0f);
    float a0 = bl[0], a1 = bl[1];
#pragma unroll
    for (int f = 0; f < 32; f++) {
        float p = pool[g * 32 + f] * inv;
        a0 += p * Wl[f * 2 + 0];
        a1 += p * Wl[f * 2 + 1];
    }
    out[g * 2 + 0] = a0;
    out[g * 2 + 1] = a1;
}

extern "C" void kernel_launch(void* const* d_in, const int* in_sizes, int n_in,
                              void* d_out, int out_size, void* d_ws, size_t ws_size,
                              hipStream_t stream) {
    const float* x    = (const float*)d_in[0];
    const int*   ei   = (const int*)d_in[1];
    const int*   batch= (const int*)d_in[2];
    const float* W1   = (const float*)d_in[3];
    const float* b1   = (const float*)d_in[4];
    const float* W2   = (const float*)d_in[5];
    const float* b2   = (const float*)d_in[6];
    const float* Wl   = (const float*)d_in[7];
    const float* bl   = (const float*)d_in[8];
    float* out = (float*)d_out;

    char* w = (char*)d_ws;
    size_t off = 0;
    auto take = [&](size_t bytes) -> char* {
        char* p = w + off;
        off = (off + bytes + 255) & ~(size_t)255;
        return p;
    };
    __hip_bfloat16* H1s    = (__hip_bfloat16*)take((size_t)N_NODES * 32 * 2);
    // packed (14.4 MB) and H2s (6.4 MB) alias: packed dies at k_csr,
    // H2s is born in k_gather1.
    char*           shared = take((size_t)NBUK * CAP * 4);
    unsigned*       packed = (unsigned*)shared;
    __hip_bfloat16* H2s    = (__hip_bfloat16*)shared;
    int*      csr    = (int*)  take((size_t)NBUK * CAP * 4);
    float*    dinv   = (float*)take((size_t)N_NODES * 4);
    int*      rp     = (int*)  take((size_t)N_NODES * 4);
    int*      rpe    = (int*)  take((size_t)N_NODES * 4);
    int*      gcnt   = (int*)  take((size_t)NBUK * 4);
    float*    pool   = (float*)take((size_t)N_GRAPHS * 32 * 4);
    int*      cnt    = (int*)  take((size_t)N_GRAPHS * 4);

    hipMemsetAsync(gcnt, 0, (size_t)NBUK * 4, stream);
    hipMemsetAsync(pool, 0, (size_t)N_GRAPHS * 32 * 4, stream);
    hipMemsetAsync(cnt, 0, (size_t)N_GRAPHS * 4, stream);

    k_binfill<<<FILL_BLOCKS, 1024, 0, stream>>>(ei, gcnt, packed);
    k_csr    <<<NBUK, 512, 0, stream>>>(packed, gcnt, batch, rp, rpe, dinv, csr, cnt);
    k_gemm1  <<<N_NODES / 32, 256, 0, stream>>>(x, W1, dinv, H1s);
    k_gather1<<<N_NODES / 4, 256, 0, stream>>>(H1s, dinv, rp, rpe, csr, b1, W2, H2s);
    k_gather2<<<N_NODES / 4, 256, 0, stream>>>(H2s, dinv, rp, rpe, csr, b2, batch, pool);
    k_final  <<<2, 256, 0, stream>>>(pool, cnt, Wl, bl, out);
}

// Round 11
// 448.989 us; speedup vs baseline: 1.3422x; 1.3422x over previous
//
#include <hip/hip_runtime.h>
#include <hip/hip_bf16.h>

#define N_NODES 100000
#define N_EDGES 3200000
#define N_GRAPHS 512
#define NBUK 782               // dst buckets of 128 nodes
#define CAP 4608               // slot capacity per bucket (mean 4092, sigma~64)
#define SRC_HALF 50000
#define FILL_CHUNK 16384
#define FILL_BLOCKS ((N_EDGES + FILL_CHUNK - 1) / FILL_CHUNK)   // 196

__device__ __forceinline__ float blo(unsigned v) { return __uint_as_float(v << 16); }
__device__ __forceinline__ float bhi(unsigned v) { return __uint_as_float(v & 0xffff0000u); }

// ---------- pass 1: bin edges into fixed bucket slots (bucket = dst>>7) ----------
__global__ __launch_bounds__(1024) void k_binfill(const int* __restrict__ ei,
                                                  int* __restrict__ gcnt,
                                                  unsigned* __restrict__ packed) {
    __shared__ int h[NBUK];
    __shared__ int base[NBUK];
    int t = threadIdx.x;
    for (int i = t; i < NBUK; i += 1024) h[i] = 0;
    __syncthreads();
    int s0 = blockIdx.x * FILL_CHUNK;
    int ng = min(FILL_CHUNK, N_EDGES - s0) >> 2;
    const int4* src4 = (const int4*)(ei + s0);
    const int4* dst4 = (const int4*)(ei + N_EDGES + s0);
    int4 sv[4], dv[4];
    int  rk[4][4];
#pragma unroll
    for (int g = 0; g < 4; g++) {
        int gi = t + g * 1024;
        if (gi < ng) {
            sv[g] = src4[gi];
            dv[g] = dst4[gi];
            rk[g][0] = atomicAdd(&h[dv[g].x >> 7], 1);
            rk[g][1] = atomicAdd(&h[dv[g].y >> 7], 1);
            rk[g][2] = atomicAdd(&h[dv[g].z >> 7], 1);
            rk[g][3] = atomicAdd(&h[dv[g].w >> 7], 1);
        }
    }
    __syncthreads();
    for (int i = t; i < NBUK; i += 1024) {
        int c = h[i];
        base[i] = c ? atomicAdd(&gcnt[i], c) : 0;
    }
    __syncthreads();
#pragma unroll
    for (int g = 0; g < 4; g++) {
        int gi = t + g * 1024;
        if (gi < ng) {
            int s[4] = {sv[g].x, sv[g].y, sv[g].z, sv[g].w};
            int d[4] = {dv[g].x, dv[g].y, dv[g].z, dv[g].w};
#pragma unroll
            for (int k = 0; k < 4; k++) {
                int bk = d[k] >> 7;
                int pos = bk * CAP + base[bk] + rk[g][k];
                packed[pos] = (unsigned)s[k] | (((unsigned)d[k] & 127u) << 17);
            }
        }
    }
}

// ---------- pass 2: per-bucket sort by (node, src-half) -> rp/rpm/rpe + CSR ----------
__global__ __launch_bounds__(512) void k_csr(const unsigned* __restrict__ packed,
                                             const int* __restrict__ gcnt,
                                             const int* __restrict__ batch,
                                             int* __restrict__ rp, int* __restrict__ rpm,
                                             int* __restrict__ rpe,
                                             float* __restrict__ dinv,
                                             int* __restrict__ csr, int* __restrict__ cnt) {
    __shared__ int deg[256];   // key = dstlocal*2 + (src>=SRC_HALF)
    __shared__ int sd[256];
    __shared__ int nb0[256];
    int t = threadIdx.x;
    int b = blockIdx.x;
    if (t < 256) deg[t] = 0;
    __syncthreads();
    int n = gcnt[b];
    const unsigned* pb = packed + (size_t)b * CAP;
    unsigned pv[3][4];
    int rk[3][4];
#pragma unroll
    for (int g = 0; g < 3; g++) {
        int i0 = 4 * (t + g * 512);
        if (i0 < n) {
            uint4 p = *(const uint4*)(pb + i0);
            pv[g][0] = p.x; pv[g][1] = p.y; pv[g][2] = p.z; pv[g][3] = p.w;
#pragma unroll
            for (int k = 0; k < 4; k++)
                if (i0 + k < n) {
                    unsigned p1 = pv[g][k];
                    int key = (int)(p1 >> 17) * 2 + (((p1 & 0x1FFFFu) >= SRC_HALF) ? 1 : 0);
                    rk[g][k] = atomicAdd(&deg[key], 1);
                }
        }
    }
    __syncthreads();
    int d = (t < 256) ? deg[t] : 0;
    if (t < 256) sd[t] = d;
    __syncthreads();
    for (int off = 1; off < 256; off <<= 1) {
        int x = (t >= off && t < 256) ? sd[t - off] : 0;
        __syncthreads();
        if (t < 256) sd[t] += x;
        __syncthreads();
    }
    if (t < 256) nb0[t] = b * CAP + sd[t] - d;
    __syncthreads();
    if (t < 128) {
        int node = b * 128 + t;
        if (node < N_NODES) {
            int lo = deg[2 * t], hi = deg[2 * t + 1];
            rp[node]  = nb0[2 * t];
            rpm[node] = nb0[2 * t + 1];
            rpe[node] = nb0[2 * t + 1] + hi;
            dinv[node] = rsqrtf((float)(lo + hi) + 1.0f);
            atomicAdd(&cnt[batch[node]], 1);
        }
    }
    __syncthreads();
#pragma unroll
    for (int g = 0; g < 3; g++) {
        int i0 = 4 * (t + g * 512);
        if (i0 < n) {
#pragma unroll
            for (int k = 0; k < 4; k++) {
                if (i0 + k < n) {
                    unsigned p = pv[g][k];
                    int key = (int)(p >> 17) * 2 + (((p & 0x1FFFFu) >= SRC_HALF) ? 1 : 0);
                    csr[nb0[key] + rk[g][k]] = (int)(p & 0x1FFFFu);
                }
            }
        }
    }
}

// ---------- H1s = bf16( (x @ W1) * dinv[row] ) ----------
__global__ void k_gemm1(const float* __restrict__ x, const float* __restrict__ W1,
                        const float* __restrict__ dinv, __hip_bfloat16* __restrict__ H1s) {
    __shared__ float Ws[128 * 32];
    __shared__ float xs[32 * 128];
    int t = threadIdx.x;
    const float4* W4 = (const float4*)W1;
    float4* Ws4 = (float4*)Ws;
#pragma unroll
    for (int i = 0; i < 4; i++) Ws4[t + 256 * i] = W4[t + 256 * i];
    int row0 = blockIdx.x * 32;
    const float4* x4 = (const float4*)(x + (size_t)row0 * 128);
    float4* xs4 = (float4*)xs;
#pragma unroll
    for (int i = 0; i < 4; i++) xs4[t + 256 * i] = x4[t + 256 * i];
    __syncthreads();
    int col = t & 31;
    int rb = (t >> 5) * 4;
    float a0 = 0.f, a1 = 0.f, a2 = 0.f, a3 = 0.f;
#pragma unroll 8
    for (int k = 0; k < 128; k++) {
        float w = Ws[k * 32 + col];
        a0 += xs[(rb + 0) * 128 + k] * w;
        a1 += xs[(rb + 1) * 128 + k] * w;
        a2 += xs[(rb + 2) * 128 + k] * w;
        a3 += xs[(rb + 3) * 128 + k] * w;
    }
    int r = row0 + rb;
    __hip_bfloat16* o = H1s + (size_t)r * 32 + col;
    o[0]  = __float2bfloat16(a0 * dinv[r + 0]);
    o[32] = __float2bfloat16(a1 * dinv[r + 1]);
    o[64] = __float2bfloat16(a2 * dinv[r + 2]);
    o[96] = __float2bfloat16(a3 * dinv[r + 3]);
}

// ---------- gather pass A: sum lo-src edges [rp,rpm) -> partial (f32) ----------
// R9 lane layout: f2 = lane&15 (bf16 pair), q = lane>>4 (4 edge slots).
__global__ void k_gatherA(const __hip_bfloat16* __restrict__ Hs,
                          const int* __restrict__ rp, const int* __restrict__ rpm,
                          const int* __restrict__ csr, float* __restrict__ part) {
    int wid = (blockIdx.x * 256 + threadIdx.x) >> 6;
    if (wid >= N_NODES) return;
    const unsigned* H32 = (const unsigned*)Hs;
    int lane = threadIdx.x & 63;
    int f2 = lane & 15;
    int q = lane >> 4;
    int beg = rp[wid], end = rpm[wid];
    float ax = 0.f, ay = 0.f;
    int e = beg + q;
    for (; e + 12 < end; e += 16) {
        int s0 = csr[e];
        int s1 = csr[e + 4];
        int s2 = csr[e + 8];
        int s3 = csr[e + 12];
        unsigned v0 = H32[(size_t)s0 * 16 + f2];
        unsigned v1 = H32[(size_t)s1 * 16 + f2];
        unsigned v2 = H32[(size_t)s2 * 16 + f2];
        unsigned v3 = H32[(size_t)s3 * 16 + f2];
        ax += blo(v0) + blo(v1) + blo(v2) + blo(v3);
        ay += bhi(v0) + bhi(v1) + bhi(v2) + bhi(v3);
    }
    for (; e < end; e += 4) {
        unsigned v = H32[(size_t)csr[e] * 16 + f2];
        ax += blo(v); ay += bhi(v);
    }
    ax += __shfl_xor(ax, 16); ay += __shfl_xor(ay, 16);
    ax += __shfl_xor(ax, 32); ay += __shfl_xor(ay, 32);
    if (q == 0)
        *(float2*)(part + (size_t)wid * 32 + f2 * 2) = make_float2(ax, ay);
}

// ---------- gather1 pass B: hi-src edges + partial, FUSED layer-2 transform ----------
__global__ void k_gather1B(const __hip_bfloat16* __restrict__ Hs, const float* __restrict__ dinv,
                           const int* __restrict__ rpm, const int* __restrict__ rpe,
                           const int* __restrict__ csr, const float* __restrict__ part,
                           const float* __restrict__ b1, const float* __restrict__ W2,
                           __hip_bfloat16* __restrict__ H2s) {
    int wid = (blockIdx.x * 256 + threadIdx.x) >> 6;
    if (wid >= N_NODES) return;
    const unsigned* H32 = (const unsigned*)Hs;
    int lane = threadIdx.x & 63;
    int f2 = lane & 15;
    int q = lane >> 4;
    int f = lane & 31;
    int half = lane >> 5;
    float w2r[16];
#pragma unroll
    for (int j = 0; j < 16; j++) w2r[j] = W2[(half * 16 + j) * 32 + f];
    int beg = rpm[wid], end = rpe[wid];
    float ax = 0.f, ay = 0.f;
    int e = beg + q;
    for (; e + 12 < end; e += 16) {
        int s0 = csr[e];
        int s1 = csr[e + 4];
        int s2 = csr[e + 8];
        int s3 = csr[e + 12];
        unsigned v0 = H32[(size_t)s0 * 16 + f2];
        unsigned v1 = H32[(size_t)s1 * 16 + f2];
        unsigned v2 = H32[(size_t)s2 * 16 + f2];
        unsigned v3 = H32[(size_t)s3 * 16 + f2];
        ax += blo(v0) + blo(v1) + blo(v2) + blo(v3);
        ay += bhi(v0) + bhi(v1) + bhi(v2) + bhi(v3);
    }
    for (; e < end; e += 4) {
        unsigned v = H32[(size_t)csr[e] * 16 + f2];
        ax += blo(v); ay += bhi(v);
    }
    ax += __shfl_xor(ax, 16); ay += __shfl_xor(ay, 16);
    ax += __shfl_xor(ax, 32); ay += __shfl_xor(ay, 32);   // allreduce
    float2 pp = *(const float2*)(part + (size_t)wid * 32 + f2 * 2);
    ax += pp.x; ay += pp.y;
    float di = dinv[wid];
    unsigned vw = H32[(size_t)wid * 16 + f2];
    float2 bb = *(const float2*)(b1 + f2 * 2);
    float vx = fmaxf((ax + blo(vw)) * di + bb.x, 0.f);
    float vy = fmaxf((ay + bhi(vw)) * di + bb.y, 0.f);
    float acc = 0.f;
#pragma unroll
    for (int j = 0; j < 16; j += 2) {
        int sl = half * 8 + (j >> 1);
        acc += __shfl(vx, sl) * w2r[j];
        acc += __shfl(vy, sl) * w2r[j + 1];
    }
    acc += __shfl_xor(acc, 32);
    if (half == 0)
        H2s[(size_t)wid * 32 + f] = __float2bfloat16(acc * di);
}

// ---------- gather2 pass B: hi-src edges + partial, fused mean-pool numerator ----------
__global__ void k_gather2B(const __hip_bfloat16* __restrict__ Hs, const float* __restrict__ dinv,
                           const int* __restrict__ rpm, const int* __restrict__ rpe,
                           const int* __restrict__ csr, const float* __restrict__ part,
                           const float* __restrict__ bias, const int* __restrict__ batch,
                           float* __restrict__ pool) {
    int wid = (blockIdx.x * 256 + threadIdx.x) >> 6;
    if (wid >= N_NODES) return;
    const unsigned* H32 = (const unsigned*)Hs;
    int lane = threadIdx.x & 63;
    int f2 = lane & 15;
    int q = lane >> 4;
    int beg = rpm[wid], end = rpe[wid];
    float ax = 0.f, ay = 0.f;
    int e = beg + q;
    for (; e + 12 < end; e += 16) {
        int s0 = csr[e];
        int s1 = csr[e + 4];
        int s2 = csr[e + 8];
        int s3 = csr[e + 12];
        unsigned v0 = H32[(size_t)s0 * 16 + f2];
        unsigned v1 = H32[(size_t)s1 * 16 + f2];
        unsigned v2 = H32[(size_t)s2 * 16 + f2];
        unsigned v3 = H32[(size_t)s3 * 16 + f2];
        ax += blo(v0) + blo(v1) + blo(v2) + blo(v3);
        ay += bhi(v0) + bhi(v1) + bhi(v2) + bhi(v3);
    }
    for (; e < end; e += 4) {
        unsigned v = H32[(size_t)csr[e] * 16 + f2];
        ax += blo(v); ay += bhi(v);
    }
    ax += __shfl_xor(ax, 16); ay += __shfl_xor(ay, 16);
    ax += __shfl_xor(ax, 32); ay += __shfl_xor(ay, 32);
    if (q == 0) {
        float2 pp = *(const float2*)(part + (size_t)wid * 32 + f2 * 2);
        ax += pp.x; ay += pp.y;
        float di = dinv[wid];
        unsigned vw = H32[(size_t)wid * 16 + f2];
        float2 bb = *(const float2*)(bias + f2 * 2);
        float vx = fmaxf((ax + blo(vw)) * di + bb.x, 0.f);
        float vy = fmaxf((ay + bhi(vw)) * di + bb.y, 0.f);
        int g = batch[wid];
        atomicAdd(&pool[(size_t)g * 32 + f2 * 2 + 0], vx);
        atomicAdd(&pool[(size_t)g * 32 + f2 * 2 + 1], vy);
    }
}

// ---------- head ----------
__global__ void k_final(const float* __restrict__ pool, const int* __restrict__ cnt,
                        const float* __restrict__ Wl, const float* __restrict__ bl,
                        float* __restrict__ out) {
    int g = blockIdx.x * 256 + threadIdx.x;
    if (g >= N_GRAPHS) return;
    float inv = 1.0f / fmaxf((float)cnt[g], 1.0f);
    float a0 = bl[0], a1 = bl[1];
#pragma unroll
    for (int f = 0; f < 32; f++) {
        float p = pool[g * 32 + f] * inv;
        a0 += p * Wl[f * 2 + 0];
        a1 += p * Wl[f * 2 + 1];
    }
    out[g * 2 + 0] = a0;
    out[g * 2 + 1] = a1;
}

extern "C" void kernel_launch(void* const* d_in, const int* in_sizes, int n_in,
                              void* d_out, int out_size, void* d_ws, size_t ws_size,
                              hipStream_t stream) {
    const float* x    = (const float*)d_in[0];
    const int*   ei   = (const int*)d_in[1];
    const int*   batch= (const int*)d_in[2];
    const float* W1   = (const float*)d_in[3];
    const float* b1   = (const float*)d_in[4];
    const float* W2   = (const float*)d_in[5];
    const float* b2   = (const float*)d_in[6];
    const float* Wl   = (const float*)d_in[7];
    const float* bl   = (const float*)d_in[8];
    float* out = (float*)d_out;

    char* w = (char*)d_ws;
    size_t off = 0;
    auto take = [&](size_t bytes) -> char* {
        char* p = w + off;
        off = (off + bytes + 255) & ~(size_t)255;
        return p;
    };
    __hip_bfloat16* H1s    = (__hip_bfloat16*)take((size_t)N_NODES * 32 * 2);
    // packed (14.4 MB) and H2s (6.4 MB) alias: packed dies at k_csr,
    // H2s is born in k_gather1B.
    char*           shared = take((size_t)NBUK * CAP * 4);
    unsigned*       packed = (unsigned*)shared;
    __hip_bfloat16* H2s    = (__hip_bfloat16*)shared;
    int*      csr    = (int*)  take((size_t)NBUK * CAP * 4);
    float*    part   = (float*)take((size_t)N_NODES * 32 * 4);
    float*    dinv   = (float*)take((size_t)N_NODES * 4);
    int*      rp     = (int*)  take((size_t)N_NODES * 4);
    int*      rpm    = (int*)  take((size_t)N_NODES * 4);
    int*      rpe    = (int*)  take((size_t)N_NODES * 4);
    int*      gcnt   = (int*)  take((size_t)NBUK * 4);
    float*    pool   = (float*)take((size_t)N_GRAPHS * 32 * 4);
    int*      cnt    = (int*)  take((size_t)N_GRAPHS * 4);

    hipMemsetAsync(gcnt, 0, (size_t)NBUK * 4, stream);
    hipMemsetAsync(pool, 0, (size_t)N_GRAPHS * 32 * 4, stream);
    hipMemsetAsync(cnt, 0, (size_t)N_GRAPHS * 4, stream);

    k_binfill <<<FILL_BLOCKS, 1024, 0, stream>>>(ei, gcnt, packed);
    k_csr     <<<NBUK, 512, 0, stream>>>(packed, gcnt, batch, rp, rpm, rpe, dinv, csr, cnt);
    k_gemm1   <<<N_NODES / 32, 256, 0, stream>>>(x, W1, dinv, H1s);
    k_gatherA <<<N_NODES / 4, 256, 0, stream>>>(H1s, rp, rpm, csr, part);
    k_gather1B<<<N_NODES / 4, 256, 0, stream>>>(H1s, dinv, rpm, rpe, csr, part, b1, W2, H2s);
    k_gatherA <<<N_NODES / 4, 256, 0, stream>>>(H2s, rp, rpm, csr, part);
    k_gather2B<<<N_NODES / 4, 256, 0, stream>>>(H2s, dinv, rpm, rpe, csr, part, b2, batch, pool);
    k_final   <<<2, 256, 0, stream>>>(pool, cnt, Wl, bl, out);
}